// Round 1
// baseline (927.015 us; speedup 1.0000x reference)
//
#include <hip/hip_runtime.h>
#include <hip/hip_bf16.h>
#include <stdint.h>

// MobileViTBlockV2: B=16, C=256, H=W=64, D=256, F=512, L=2, patch 2x2.
// Strategy: channels-last bf16 activations, fp32 residual, MFMA bf16 GEMMs.
// Patchify is a pixel permutation -> never materialized; attention groups are
// the 4 pixel parity classes.

#define B_    16
#define C_    256
#define D_    256
#define F_    512
#define NPIX  4096
#define NE_PB 1048576   // D_*NPIX elements per batch for GN

typedef __attribute__((ext_vector_type(8))) short  short8;
typedef __attribute__((ext_vector_type(4))) short  short4v;
typedef __attribute__((ext_vector_type(4))) float  f32x4;

__device__ __forceinline__ float b2f(short s){
  return __uint_as_float(((unsigned)(unsigned short)s) << 16);
}
__device__ __forceinline__ short f2b(float f){
  unsigned u = __float_as_uint(f);
  return (short)((u + 0x7fffu + ((u >> 16) & 1u)) >> 16);  // RNE
}

// ---------- small prep kernels ----------
__global__ void cvt_k(const float* __restrict__ s, short* __restrict__ d, int n){
  int i = blockIdx.x*256 + threadIdx.x;
  if (i < n) d[i] = f2b(s[i]);
}
__global__ void zero_k(float* __restrict__ p, int n){
  int i = blockIdx.x*256 + threadIdx.x;
  if (i < n) p[i] = 0.f;
}

// ---------- dwconv3x3 + BN + SiLU (channel-major in, channel-major bf16 out) ----------
__global__ void dwconv_k(const float* __restrict__ X, const float* __restrict__ W,
                         const float* __restrict__ G, const float* __restrict__ Bb,
                         const float* __restrict__ Mn, const float* __restrict__ Vr,
                         short* __restrict__ O){
  const int h0 = blockIdx.x * 8;
  const int c  = blockIdx.y;
  const int b  = blockIdx.z;
  const int t  = threadIdx.x;
  __shared__ float xs[10][66];
  const float* xp = X + ((size_t)(b*C_ + c)) * NPIX;
  for (int i = t; i < 660; i += 256){
    int r = i / 66, col = i - r*66;
    int h = h0 - 1 + r, w = col - 1;
    float v = 0.f;
    if (h >= 0 && h < 64 && w >= 0 && w < 64) v = xp[h*64 + w];
    xs[r][col] = v;
  }
  __syncthreads();
  float wgt[9];
#pragma unroll
  for (int j = 0; j < 9; ++j) wgt[j] = W[c*9 + j];
  const float scale = G[c] * rsqrtf(Vr[c] + 1e-5f);
  const float mu = Mn[c], bb = Bb[c];
  short* op = O + ((size_t)(b*C_ + c)) * NPIX;
  for (int i = t; i < 512; i += 256){
    int r = i >> 6, w = i & 63;
    float s = 0.f;
#pragma unroll
    for (int dh = 0; dh < 3; ++dh)
#pragma unroll
      for (int dw = 0; dw < 3; ++dw)
        s += xs[r+dh][w+dw] * wgt[dh*3+dw];
    float y = (s - mu) * scale + bb;
    y = y / (1.f + expf(-y));          // SiLU
    op[(h0 + r)*64 + w] = f2b(y);
  }
}

// ---------- (b,c,s) -> (b,s,c) bf16 transpose ----------
__global__ void transpose_k(const short* __restrict__ I, short* __restrict__ O){
  const int s0 = blockIdx.x*32, c0 = blockIdx.y*32, b = blockIdx.z;
  const int tx = threadIdx.x & 31, ty = threadIdx.x >> 5;
  __shared__ short tile[32][33];
#pragma unroll
  for (int j = 0; j < 4; ++j)
    tile[ty + 8*j][tx] = I[((size_t)(b*C_ + c0 + ty + 8*j))*NPIX + s0 + tx];
  __syncthreads();
#pragma unroll
  for (int j = 0; j < 4; ++j)
    O[((size_t)(b*NPIX + s0 + ty + 8*j))*C_ + c0 + tx] = tile[tx][ty + 8*j];
}

// ---------- MFMA bf16 GEMM: out[m,n] = sum_k Wt[m,k]*X[n,k], 128x128 tile ----------
// EPI: 0 = write f32 P (no bias); 1 = +bias -> bf16 Obf; 2 = P += acc+bias;
//      3 = silu(acc+bias) -> bf16 Obf; 4 = BN((acc)) -> f32 channel-major Of32
template<int EPI>
__global__ __launch_bounds__(256)
void gemm_k(const short* __restrict__ A, const short* __restrict__ X,
            const int M, const int K,
            const float* __restrict__ bias,
            float* __restrict__ P,
            short* __restrict__ Obf,
            float* __restrict__ Of32,
            const float* __restrict__ bng, const float* __restrict__ bnb,
            const float* __restrict__ bnm, const float* __restrict__ bnv)
{
  const int nt = blockIdx.x, mt = blockIdx.y, b = blockIdx.z;
  const int tid  = threadIdx.x;
  const int lane = tid & 63, wave = tid >> 6;
  const int wm = (wave >> 1)*64, wn = (wave & 1)*64;
  const int lr = lane & 15, lq = lane >> 4;
  __shared__ __align__(16) short As[128*40];  // rows padded 32->40 elems (2-way max bank alias)
  __shared__ __align__(16) short Bs[128*40];
  const short* Ap = A + (size_t)mt*128*K;
  const short* Xp = X + ((size_t)b*NPIX + (size_t)nt*128) * K;
  f32x4 acc[4][4];
#pragma unroll
  for (int r = 0; r < 4; ++r)
#pragma unroll
    for (int c = 0; c < 4; ++c) acc[r][c] = (f32x4){0.f,0.f,0.f,0.f};

  const int srow = tid >> 2, sseg = tid & 3;     // 64 rows x 4 x 16B per pass
  for (int k0 = 0; k0 < K; k0 += 32){
#pragma unroll
    for (int g2 = 0; g2 < 2; ++g2){
      const int row = g2*64 + srow;
      *(short8*)&As[row*40 + sseg*8] = *(const short8*)&Ap[(size_t)row*K + k0 + sseg*8];
      *(short8*)&Bs[row*40 + sseg*8] = *(const short8*)&Xp[(size_t)row*K + k0 + sseg*8];
    }
    __syncthreads();
    short8 af[4], bfr[4];
#pragma unroll
    for (int r = 0; r < 4; ++r) af[r]  = *(const short8*)&As[(wm + r*16 + lr)*40 + lq*8];
#pragma unroll
    for (int c = 0; c < 4; ++c) bfr[c] = *(const short8*)&Bs[(wn + c*16 + lr)*40 + lq*8];
#pragma unroll
    for (int r = 0; r < 4; ++r)
#pragma unroll
      for (int c = 0; c < 4; ++c)
        acc[r][c] = __builtin_amdgcn_mfma_f32_16x16x32_bf16(af[r], bfr[c], acc[r][c], 0, 0, 0);
    __syncthreads();
  }

#pragma unroll
  for (int r = 0; r < 4; ++r){
    const int m0 = mt*128 + wm + r*16 + lq*4;
    float bia0 = 0.f, bia1 = 0.f, bia2 = 0.f, bia3 = 0.f;
    if constexpr (EPI == 1 || EPI == 2 || EPI == 3){
      bia0 = bias[m0]; bia1 = bias[m0+1]; bia2 = bias[m0+2]; bia3 = bias[m0+3];
    }
#pragma unroll
    for (int c = 0; c < 4; ++c){
      const int n = nt*128 + wn + c*16 + lr;
      const size_t pix = (size_t)b*NPIX + n;
      f32x4 v = acc[r][c];
      if constexpr (EPI == 0){
        *(f32x4*)&P[pix*(size_t)M + m0] = v;
      } else if constexpr (EPI == 1){
        short4v o;
        o.x = f2b(v.x + bia0); o.y = f2b(v.y + bia1);
        o.z = f2b(v.z + bia2); o.w = f2b(v.w + bia3);
        *(short4v*)&Obf[pix*(size_t)M + m0] = o;
      } else if constexpr (EPI == 2){
        f32x4* pp = (f32x4*)&P[pix*(size_t)M + m0];
        f32x4 old = *pp;
        old.x += v.x + bia0; old.y += v.y + bia1;
        old.z += v.z + bia2; old.w += v.w + bia3;
        *pp = old;
      } else if constexpr (EPI == 3){
        float t0 = v.x + bia0, t1 = v.y + bia1, t2 = v.z + bia2, t3 = v.w + bia3;
        short4v o;
        o.x = f2b(t0 / (1.f + expf(-t0)));
        o.y = f2b(t1 / (1.f + expf(-t1)));
        o.z = f2b(t2 / (1.f + expf(-t2)));
        o.w = f2b(t3 / (1.f + expf(-t3)));
        *(short4v*)&Obf[pix*(size_t)M + m0] = o;
      } else {  // EPI == 4: BN epilogue, write channel-major f32 output
        f32x4 g4 = *(const f32x4*)&bng[m0];
        f32x4 b4 = *(const f32x4*)&bnb[m0];
        f32x4 m4 = *(const f32x4*)&bnm[m0];
        f32x4 v4 = *(const f32x4*)&bnv[m0];
        float* ob = Of32 + ((size_t)(b*C_ + m0))*NPIX + n;
        ob[0*NPIX] = (v.x - m4.x) * (g4.x * rsqrtf(v4.x + 1e-5f)) + b4.x;
        ob[1*NPIX] = (v.y - m4.y) * (g4.y * rsqrtf(v4.y + 1e-5f)) + b4.y;
        ob[2*NPIX] = (v.z - m4.z) * (g4.z * rsqrtf(v4.z + 1e-5f)) + b4.z;
        ob[3*NPIX] = (v.w - m4.w) * (g4.w * rsqrtf(v4.w + 1e-5f)) + b4.w;
      }
    }
  }
}

// ---------- GN (1 group = layernorm over D*P*N per batch): stats then apply ----------
__global__ void gn_stats_k(const float* __restrict__ P, float* __restrict__ st){
  const int b = blockIdx.y;
  const size_t base = (size_t)b*NE_PB + (size_t)blockIdx.x*16384 + threadIdx.x*4;
  float sm = 0.f, ss = 0.f;
#pragma unroll
  for (int i = 0; i < 16; ++i){
    f32x4 v = *(const f32x4*)&P[base + (size_t)i*1024];
    sm += v.x + v.y + v.z + v.w;
    ss += v.x*v.x + v.y*v.y + v.z*v.z + v.w*v.w;
  }
#pragma unroll
  for (int o = 32; o > 0; o >>= 1){ sm += __shfl_down(sm, o); ss += __shfl_down(ss, o); }
  __shared__ float r1[4], r2[4];
  const int lane = threadIdx.x & 63, wv = threadIdx.x >> 6;
  if (lane == 0){ r1[wv] = sm; r2[wv] = ss; }
  __syncthreads();
  if (threadIdx.x == 0){
    atomicAdd(&st[b*2+0], r1[0]+r1[1]+r1[2]+r1[3]);
    atomicAdd(&st[b*2+1], r2[0]+r2[1]+r2[2]+r2[3]);
  }
}

__global__ void gn_apply_k(const float* __restrict__ P, const float* __restrict__ st,
                           const float* __restrict__ G, const float* __restrict__ Bb,
                           short* __restrict__ U){
  const int b = blockIdx.y;
  const float mean = st[b*2]   * (1.f/NE_PB);
  const float var  = st[b*2+1] * (1.f/NE_PB) - mean*mean;
  const float inv  = rsqrtf(var + 1e-5f);
  const int c0 = (threadIdx.x*4) & 255;
  const f32x4 g4 = *(const f32x4*)&G[c0];
  const f32x4 b4 = *(const f32x4*)&Bb[c0];
  const size_t base = (size_t)b*NE_PB + (size_t)blockIdx.x*16384 + threadIdx.x*4;
#pragma unroll
  for (int i = 0; i < 16; ++i){
    f32x4 v = *(const f32x4*)&P[base + (size_t)i*1024];
    short4v o;
    o.x = f2b((v.x - mean)*inv*g4.x + b4.x);
    o.y = f2b((v.y - mean)*inv*g4.y + b4.y);
    o.z = f2b((v.z - mean)*inv*g4.z + b4.z);
    o.w = f2b((v.w - mean)*inv*g4.w + b4.w);
    *(short4v*)&U[base + (size_t)i*1024] = o;
  }
}

// ---------- q = Wq . u + qb  (one wave per pixel) ----------
__global__ void q_k(const short* __restrict__ U, const float* __restrict__ Wq,
                    const float* __restrict__ Qb, float* __restrict__ Q){
  const int lane = threadIdx.x & 63;
  const int pix = (blockIdx.x*256 + threadIdx.x) >> 6;  // global pixel 0..65535
  short4v u4 = *(const short4v*)&U[(size_t)pix*256 + lane*4];
  f32x4  w4 = *(const f32x4*)&Wq[lane*4];
  float s = b2f(u4.x)*w4.x + b2f(u4.y)*w4.y + b2f(u4.z)*w4.z + b2f(u4.w)*w4.w;
#pragma unroll
  for (int o = 32; o > 0; o >>= 1) s += __shfl_down(s, o);
  if (lane == 0) Q[pix] = s + Qb[0];
}

// ---------- softmax over the 1024 pixels of one parity class ----------
__global__ void softmax_k(const float* __restrict__ Q, float* __restrict__ S){
  const int bp = blockIdx.x, b = bp >> 2, p = bp & 3;
  const int ph = p >> 1, pw = p & 1;
  const int t = threadIdx.x;
  float vals[4]; int ns[4];
  float mx = -1e30f;
#pragma unroll
  for (int j = 0; j < 4; ++j){
    int n = t + j*256;
    int h = 2*(n >> 5) + ph, w = 2*(n & 31) + pw;
    float q = Q[b*NPIX + h*64 + w];
    vals[j] = q; ns[j] = n;
    mx = fmaxf(mx, q);
  }
  __shared__ float red[4];
  const int lane = t & 63, wv = t >> 6;
#pragma unroll
  for (int o = 32; o > 0; o >>= 1) mx = fmaxf(mx, __shfl_down(mx, o));
  if (lane == 0) red[wv] = mx;
  __syncthreads();
  mx = fmaxf(fmaxf(red[0], red[1]), fmaxf(red[2], red[3]));
  __syncthreads();
  float sum = 0.f;
#pragma unroll
  for (int j = 0; j < 4; ++j){ vals[j] = expf(vals[j] - mx); sum += vals[j]; }
#pragma unroll
  for (int o = 32; o > 0; o >>= 1) sum += __shfl_down(sum, o);
  if (lane == 0) red[wv] = sum;
  __syncthreads();
  sum = red[0] + red[1] + red[2] + red[3];
  const float r = 1.f / sum;
#pragma unroll
  for (int j = 0; j < 4; ++j) S[bp*1024 + ns[j]] = vals[j]*r;
}

// ---------- ctx partial: ctx[b,p,c] = sum_n k[b,pix(p,n),c]*s[b,p,n] (8 chunks) ----------
__global__ void ctx_k(const short* __restrict__ KV, const float* __restrict__ S,
                      float* __restrict__ CP){
  const int bp = blockIdx.x, chunk = blockIdx.y;
  const int b = bp >> 2, p = bp & 3;
  const int ph = p >> 1, pw = p & 1;
  const int c = threadIdx.x;
  __shared__ float sl[128];
  const int n0 = chunk*128;
  if (c < 128) sl[c] = S[bp*1024 + n0 + c];
  __syncthreads();
  float acc = 0.f;
  for (int j = 0; j < 128; ++j){
    int n = n0 + j;
    int h = 2*(n >> 5) + ph, w = 2*(n & 31) + pw;
    acc += b2f(KV[((size_t)(b*NPIX) + h*64 + w)*512 + c]) * sl[j];
  }
  CP[(size_t)(bp*8 + chunk)*256 + c] = acc;
}

__global__ void ctx_sum_k(const float* __restrict__ CP, float* __restrict__ CT){
  const int bp = blockIdx.x, c = threadIdx.x;
  float s = 0.f;
#pragma unroll
  for (int j = 0; j < 8; ++j) s += CP[(size_t)(bp*8 + j)*256 + c];
  CT[bp*256 + c] = s;
}

// ---------- attn input: relu(v) * ctx[parity] -> bf16 channels-last ----------
__global__ void attn_in_k(const short* __restrict__ KV, const float* __restrict__ CT,
                          short* __restrict__ O){
  const size_t vid = (size_t)blockIdx.x*256 + threadIdx.x;  // 4-channel vectors
  const int c4  = (int)(vid & 63);
  const int pix = (int)((vid >> 6) & 4095);
  const int b   = (int)(vid >> 18);
  const int h = pix >> 6, w = pix & 63;
  const int par = (h & 1)*2 + (w & 1);
  short4v v4 = *(const short4v*)&KV[((size_t)(b*NPIX) + pix)*512 + 256 + c4*4];
  f32x4  cx = *(const f32x4*)&CT[(b*4 + par)*256 + c4*4];
  short4v o;
  o.x = f2b(fmaxf(b2f(v4.x), 0.f)*cx.x);
  o.y = f2b(fmaxf(b2f(v4.y), 0.f)*cx.y);
  o.z = f2b(fmaxf(b2f(v4.z), 0.f)*cx.z);
  o.w = f2b(fmaxf(b2f(v4.w), 0.f)*cx.w);
  *(short4v*)&O[((size_t)(b*NPIX) + pix)*256 + c4*4] = o;
}

extern "C" void kernel_launch(void* const* d_in, const int* in_sizes, int n_in,
                              void* d_out, int out_size, void* d_ws, size_t ws_size,
                              hipStream_t stream){
  const float* x      = (const float*)d_in[0];
  const float* dw_w   = (const float*)d_in[1];
  const float* dw_g   = (const float*)d_in[2];
  const float* dw_b   = (const float*)d_in[3];
  const float* dw_m   = (const float*)d_in[4];
  const float* dw_v   = (const float*)d_in[5];
  const float* pw_w   = (const float*)d_in[6];
  const float* gn1_g  = (const float*)d_in[7];
  const float* gn1_b  = (const float*)d_in[8];
  const float* qkv_w  = (const float*)d_in[9];
  const float* qkv_b  = (const float*)d_in[10];
  const float* out_w  = (const float*)d_in[11];
  const float* out_b  = (const float*)d_in[12];
  const float* gn2_g  = (const float*)d_in[13];
  const float* gn2_b  = (const float*)d_in[14];
  const float* ffn1_w = (const float*)d_in[15];
  const float* ffn1_b = (const float*)d_in[16];
  const float* ffn2_w = (const float*)d_in[17];
  const float* ffn2_b = (const float*)d_in[18];
  const float* gnf_g  = (const float*)d_in[19];
  const float* gnf_b  = (const float*)d_in[20];
  const float* proj_w = (const float*)d_in[21];
  const float* pbn_g  = (const float*)d_in[22];
  const float* pbn_b  = (const float*)d_in[23];
  const float* pbn_m  = (const float*)d_in[24];
  const float* pbn_v  = (const float*)d_in[25];
  float* out = (float*)d_out;

  uint8_t* w8 = (uint8_t*)d_ws;
  float* P     = (float*)(w8);                 // fp32 residual, 64 MiB
  short* bufA  = (short*)(w8 + 67108864);      // bf16 (B,4096,256), 32 MiB
  short* bufB  = (short*)(w8 + 100663296);     // bf16 (B,4096,512), 64 MiB
  short* w_pw  = (short*)(w8 + 167772160);
  short* w_qkv = (short*)(w8 + 167903232);
  short* w_out = (short*)(w8 + 168428544);
  short* w_f1  = (short*)(w8 + 168690688);
  short* w_f2  = (short*)(w8 + 169214976);
  short* w_pj  = (short*)(w8 + 169739264);
  float* qbuf  = (float*)(w8 + 169870336);     // (B*4096)
  float* scor  = (float*)(w8 + 170132480);     // (64,1024)
  float* ctxp  = (float*)(w8 + 170394624);     // (64,8,256)
  float* ctxs  = (float*)(w8 + 170918912);     // (64,256)
  float* stats = (float*)(w8 + 170984448);     // 5 sites x 16 x 2

  // weight casts + stat zeroing (runs every call; cheap)
  cvt_k<<<256, 256, 0, stream>>>(pw_w,   w_pw,  65536);
  cvt_k<<<1027, 256, 0, stream>>>(qkv_w, w_qkv, 262656);
  cvt_k<<<512, 256, 0, stream>>>(out_w,  w_out, 131072);
  cvt_k<<<1024, 256, 0, stream>>>(ffn1_w, w_f1, 262144);
  cvt_k<<<1024, 256, 0, stream>>>(ffn2_w, w_f2, 262144);
  cvt_k<<<256, 256, 0, stream>>>(proj_w, w_pj,  65536);
  zero_k<<<1, 256, 0, stream>>>(stats, 160);

  dwconv_k<<<dim3(8,256,16), 256, 0, stream>>>(x, dw_w, dw_g, dw_b, dw_m, dw_v, bufB);
  transpose_k<<<dim3(128,8,16), 256, 0, stream>>>(bufB, bufA);
  // pw conv -> fp32 residual P
  gemm_k<0><<<dim3(32,2,16), 256, 0, stream>>>(w_pw, bufA, 256, 256, nullptr, P,
                                               nullptr, nullptr, nullptr, nullptr, nullptr, nullptr);

  for (int i = 0; i < 2; ++i){
    float* st1 = stats + (2*i)*32;
    gn_stats_k<<<dim3(64,16), 256, 0, stream>>>(P, st1);
    gn_apply_k<<<dim3(64,16), 256, 0, stream>>>(P, st1, gn1_g + i*256, gn1_b + i*256, bufA);
    q_k<<<16384, 256, 0, stream>>>(bufA, qkv_w + i*513*256, qkv_b + i*513, qbuf);
    gemm_k<1><<<dim3(32,4,16), 256, 0, stream>>>(w_qkv + (i*513+1)*256, bufA, 512, 256,
                                                 qkv_b + i*513 + 1, nullptr, bufB, nullptr,
                                                 nullptr, nullptr, nullptr, nullptr);
    softmax_k<<<64, 256, 0, stream>>>(qbuf, scor);
    ctx_k<<<dim3(64,8), 256, 0, stream>>>(bufB, scor, ctxp);
    ctx_sum_k<<<64, 256, 0, stream>>>(ctxp, ctxs);
    attn_in_k<<<16384, 256, 0, stream>>>(bufB, ctxs, bufA);
    gemm_k<2><<<dim3(32,2,16), 256, 0, stream>>>(w_out + i*65536, bufA, 256, 256,
                                                 out_b + i*256, P, nullptr, nullptr,
                                                 nullptr, nullptr, nullptr, nullptr);
    float* st2 = stats + (2*i+1)*32;
    gn_stats_k<<<dim3(64,16), 256, 0, stream>>>(P, st2);
    gn_apply_k<<<dim3(64,16), 256, 0, stream>>>(P, st2, gn2_g + i*256, gn2_b + i*256, bufA);
    gemm_k<3><<<dim3(32,4,16), 256, 0, stream>>>(w_f1 + i*131072, bufA, 512, 256,
                                                 ffn1_b + i*512, nullptr, bufB, nullptr,
                                                 nullptr, nullptr, nullptr, nullptr);
    gemm_k<2><<<dim3(32,2,16), 256, 0, stream>>>(w_f2 + i*131072, bufB, 256, 512,
                                                 ffn2_b + i*256, P, nullptr, nullptr,
                                                 nullptr, nullptr, nullptr, nullptr);
  }

  float* st = stats + 4*32;
  gn_stats_k<<<dim3(64,16), 256, 0, stream>>>(P, st);
  gn_apply_k<<<dim3(64,16), 256, 0, stream>>>(P, st, gnf_g, gnf_b, bufA);
  gemm_k<4><<<dim3(32,2,16), 256, 0, stream>>>(w_pj, bufA, 256, 256, nullptr,
                                               nullptr, nullptr, out,
                                               pbn_g, pbn_b, pbn_m, pbn_v);

  (void)in_sizes; (void)n_in; (void)out_size; (void)ws_size;
}